// Round 10
// baseline (458.328 us; speedup 1.0000x reference)
//
#include <hip/hip_runtime.h>

typedef unsigned int u32;
typedef unsigned short u16;
typedef __attribute__((ext_vector_type(8))) short short8;   // 8 bf16 (4 VGPRs)
typedef __attribute__((ext_vector_type(4))) float f32x4;    // MFMA acc

#define DIM 128      // 4 factors * 32 cols
#define ROW_DW 64    // fac row = 64 dwords (bf16 pairs)

__device__ __forceinline__ float bf_lo(u32 u){ return __uint_as_float(u << 16); }
__device__ __forceinline__ float bf_hi(u32 u){ return __uint_as_float(u & 0xffff0000u); }
__device__ __forceinline__ u16 f2bf(float x){
  u32 u = __float_as_uint(x);
  return (u16)((u + 0x7fffu + ((u >> 16) & 1u)) >> 16);  // RNE
}

__global__ void zero_int_kernel(int* p, int n){
  int i = blockIdx.x * blockDim.x + threadIdx.x;
  if (i < n) p[i] = 0;
}

// B fragments for mfma_f32_16x16x32_bf16, layout [kt][ct][lane][j]:
// frag = bf16( W[f][d][k] + b[f][k] ) at d = kt*32+(lane>>4)*8+j, c = ct*16+(lane&15)
__global__ void prep_bfrag_kernel(const float* __restrict__ W, const float* __restrict__ B,
                                  u16* __restrict__ frag){
  int i = blockIdx.x * 256 + threadIdx.x;       // 4*8*64*8 = 16384
  if (i >= 16384) return;
  int j = i & 7, lane = (i >> 3) & 63, ct = (i >> 9) & 7, kt = i >> 12;
  int d = kt * 32 + (lane >> 4) * 8 + j;
  int c = ct * 16 + (lane & 15);
  int f = c >> 5, k = c & 31;
  frag[i] = f2bf(W[f * 4096 + d * 32 + k] + B[f * 32 + k]);  // W:(4,128,32) b:(4,1,32)
}

// fac = l2norm_f(leaky(emb @ wb)) via MFMA. Wave handles 16 nodes x 128 cols.
__global__ __launch_bounds__(256) void fac_mfma_kernel(const float* __restrict__ emb,
                                                       const short8* __restrict__ bfrag,
                                                       u16* __restrict__ fac, int N){
  int lane = threadIdx.x & 63;
  int nb = blockIdx.x * 64 + (threadIdx.x >> 6) * 16;
  if (nb >= N) return;
  int quad = lane >> 4, lo = lane & 15;
  int arow = nb + lo; if (arow >= N) arow = N - 1;
  const float* ap = emb + (size_t)arow * DIM + quad * 8;
  f32x4 acc[8];
#pragma unroll
  for (int ct = 0; ct < 8; ++ct) acc[ct] = (f32x4){0.f, 0.f, 0.f, 0.f};
#pragma unroll
  for (int kt = 0; kt < 4; ++kt) {
    float4 e0 = *(const float4*)(ap + kt * 32);
    float4 e1 = *(const float4*)(ap + kt * 32 + 4);
    short8 afr;
    afr[0] = (short)f2bf(e0.x); afr[1] = (short)f2bf(e0.y);
    afr[2] = (short)f2bf(e0.z); afr[3] = (short)f2bf(e0.w);
    afr[4] = (short)f2bf(e1.x); afr[5] = (short)f2bf(e1.y);
    afr[6] = (short)f2bf(e1.z); afr[7] = (short)f2bf(e1.w);
#pragma unroll
    for (int ct = 0; ct < 8; ++ct) {
      short8 bfr = bfrag[(kt * 8 + ct) * 64 + lane];
      acc[ct] = __builtin_amdgcn_mfma_f32_16x16x32_bf16(afr, bfr, acc[ct], 0, 0, 0);
    }
  }
  float v[8][4];
#pragma unroll
  for (int ct = 0; ct < 8; ++ct)
#pragma unroll
    for (int i = 0; i < 4; ++i) {
      float x = acc[ct][i];
      v[ct][i] = x > 0.f ? x : 0.2f * x;
    }
  float inv[4][4];   // [i][f]
#pragma unroll
  for (int i = 0; i < 4; ++i)
#pragma unroll
    for (int f = 0; f < 4; ++f) {
      float ss = v[2 * f][i] * v[2 * f][i] + v[2 * f + 1][i] * v[2 * f + 1][i];
      ss += __shfl_xor(ss, 1); ss += __shfl_xor(ss, 2);
      ss += __shfl_xor(ss, 4); ss += __shfl_xor(ss, 8);
      inv[i][f] = 1.0f / fmaxf(sqrtf(ss), 1e-12f);
    }
#pragma unroll
  for (int i = 0; i < 4; ++i) {
    int node = nb + quad * 4 + i;
    if (node >= N) continue;
#pragma unroll
    for (int ct = 0; ct < 8; ++ct)
      fac[(size_t)node * DIM + ct * 16 + lo] = f2bf(v[ct][i] * inv[i][ct >> 1]);
  }
}

// XCD-partitioned histogram: block (b&7) handles rows with part(r)==(b&7).
__global__ void hist_kernel(const int* __restrict__ row, int* __restrict__ cnt,
                            int E, int N, float pscale){
  int xcd = blockIdx.x & 7;
  int base = (blockIdx.x >> 3) * blockDim.x + threadIdx.x;
  int stride = (gridDim.x >> 3) * blockDim.x;
  for (int e = base; e < E; e += stride) {
    int r = row[e];
    if ((u32)r >= (u32)N) continue;
    int part = (int)((float)r * pscale);
    part = part > 7 ? 7 : part;
    if (part != xcd) continue;
    atomicAdd(&cnt[r], 1);
  }
}

// ---- 3-phase exclusive scan of cnt[0..N) -> offs[0..N], bsum scratch ----
__global__ __launch_bounds__(256) void scan1_kernel(const int* __restrict__ cnt,
                                                    int* __restrict__ offs,
                                                    int* __restrict__ bsum, int N){
  __shared__ int sh[256];
  int tid = threadIdx.x;
  int idx = blockIdx.x * 1024 + tid * 4;
  int v0 = (idx     < N) ? cnt[idx]     : 0;
  int v1 = (idx + 1 < N) ? cnt[idx + 1] : 0;
  int v2 = (idx + 2 < N) ? cnt[idx + 2] : 0;
  int v3 = (idx + 3 < N) ? cnt[idx + 3] : 0;
  sh[tid] = v0 + v1 + v2 + v3;
  __syncthreads();
  for (int off = 1; off < 256; off <<= 1) {
    int v = (tid >= off) ? sh[tid - off] : 0;
    __syncthreads();
    sh[tid] += v;
    __syncthreads();
  }
  int ex = (tid == 0) ? 0 : sh[tid - 1];
  if (tid == 255) bsum[blockIdx.x] = sh[255];
  if (idx     < N) offs[idx]     = ex;
  if (idx + 1 < N) offs[idx + 1] = ex + v0;
  if (idx + 2 < N) offs[idx + 2] = ex + v0 + v1;
  if (idx + 3 < N) offs[idx + 3] = ex + v0 + v1 + v2;
}

__global__ __launch_bounds__(1024) void scan2_kernel(int* __restrict__ bsum, int B){
  __shared__ int sh[1024];
  int tid = threadIdx.x;
  sh[tid] = (tid < B) ? bsum[tid] : 0;
  __syncthreads();
  for (int off = 1; off < 1024; off <<= 1) {
    int v = (tid >= off) ? sh[tid - off] : 0;
    __syncthreads();
    sh[tid] += v;
    __syncthreads();
  }
  if (tid < B) bsum[tid] = (tid == 0) ? 0 : sh[tid - 1];
  if (tid == B - 1) bsum[B] = sh[tid];
}

__global__ void scan3_kernel(int* __restrict__ offs, const int* __restrict__ bsum,
                             int* __restrict__ cur, int N, int B){
  int i = blockIdx.x * blockDim.x + threadIdx.x;
  if (i < N) {
    int v = offs[i] + bsum[i >> 10];
    offs[i] = v;
    cur[i] = v;
  }
  if (i == 0) offs[N] = bsum[B];
}

// XCD-partitioned scatter: ccol lines for a row-range stay in one XCD's L2.
__global__ void scatter_kernel(const int* __restrict__ row, const int* __restrict__ col,
                               int* __restrict__ cur, int* __restrict__ ccol,
                               int E, int N, float pscale){
  int xcd = blockIdx.x & 7;
  int base = (blockIdx.x >> 3) * blockDim.x + threadIdx.x;
  int stride = (gridDim.x >> 3) * blockDim.x;
  for (int e = base; e < E; e += stride) {
    int r = row[e];
    if ((u32)r >= (u32)N) continue;
    int part = (int)((float)r * pscale);
    part = part > 7 ? 7 : part;
    if (part != xcd) continue;
    int pos = atomicAdd(&cur[r], 1);
    if ((u32)pos < (u32)E) ccol[pos] = col[e];
  }
}

// One wave per node; each 8-lane slot owns one edge (8 in flight).
// Lane (s,k): comps [16k,16k+16) (all in factor k>>1). Per edge: 16-FMA partial
// dot -> 1 shfl reduce -> softmax over factors with ONE exp + shfl max/sum ->
// acc += p*tail. Epilogue: slot merge (xor 8/16/32), +fac[n], per-factor l2norm.
__global__ __launch_bounds__(256) void edge_kernel(const void* __restrict__ headp,
                                                   int head_is_bf16,
                                                   const u32* __restrict__ fac,
                                                   const int* __restrict__ offs,
                                                   const int* __restrict__ ccol,
                                                   float* __restrict__ outp, int N, int E){
  int lane = threadIdx.x & 63;
  int n = blockIdx.x * 4 + (threadIdx.x >> 6);
  if (n >= N) return;
  int s = lane >> 3, k = lane & 7;
  float h[16];
  if (head_is_bf16) {
    const u32* hp = (const u32*)headp + (size_t)n * ROW_DW + 8 * k;
    uint4 x0 = *(const uint4*)hp, x1 = *(const uint4*)(hp + 4);
    h[0]=bf_lo(x0.x); h[1]=bf_hi(x0.x); h[2]=bf_lo(x0.y); h[3]=bf_hi(x0.y);
    h[4]=bf_lo(x0.z); h[5]=bf_hi(x0.z); h[6]=bf_lo(x0.w); h[7]=bf_hi(x0.w);
    h[8]=bf_lo(x1.x); h[9]=bf_hi(x1.x); h[10]=bf_lo(x1.y); h[11]=bf_hi(x1.y);
    h[12]=bf_lo(x1.z); h[13]=bf_hi(x1.z); h[14]=bf_lo(x1.w); h[15]=bf_hi(x1.w);
  } else {
    const float* hp = (const float*)headp + (size_t)n * DIM + 16 * k;
    float4 y0 = *(const float4*)hp,       y1 = *(const float4*)(hp + 4);
    float4 y2 = *(const float4*)(hp + 8), y3 = *(const float4*)(hp + 12);
    h[0]=y0.x; h[1]=y0.y; h[2]=y0.z; h[3]=y0.w; h[4]=y1.x; h[5]=y1.y; h[6]=y1.z; h[7]=y1.w;
    h[8]=y2.x; h[9]=y2.y; h[10]=y2.z; h[11]=y2.w; h[12]=y3.x; h[13]=y3.y; h[14]=y3.z; h[15]=y3.w;
  }
  float a[16];
#pragma unroll
  for (int j = 0; j < 16; ++j) a[j] = 0.f;
  int beg = offs[n], end = offs[n + 1];
  if (beg < 0) beg = 0;
  if (end > E) end = E;
  for (int e0 = beg; e0 < end; e0 += 8) {
    int e = e0 + s;
    int valid = (e < end) ? 1 : 0;
    int c = valid ? ccol[e] : 0;
    if ((u32)c >= (u32)N) c = 0;
    const u32* rp = fac + (size_t)c * ROW_DW + 8 * k;
    uint4 v0 = *(const uint4*)rp, v1 = *(const uint4*)(rp + 4);
    float t[16];
    t[0]=bf_lo(v0.x); t[1]=bf_hi(v0.x); t[2]=bf_lo(v0.y); t[3]=bf_hi(v0.y);
    t[4]=bf_lo(v0.z); t[5]=bf_hi(v0.z); t[6]=bf_lo(v0.w); t[7]=bf_hi(v0.w);
    t[8]=bf_lo(v1.x); t[9]=bf_hi(v1.x); t[10]=bf_lo(v1.y); t[11]=bf_hi(v1.y);
    t[12]=bf_lo(v1.z); t[13]=bf_hi(v1.z); t[14]=bf_lo(v1.w); t[15]=bf_hi(v1.w);
    float dp = 0.f;
#pragma unroll
    for (int j = 0; j < 16; ++j) dp = fmaf(h[j], t[j], dp);
    dp += __shfl_xor(dp, 1);                       // full 32-comp dot of factor k>>1
    float m = fmaxf(dp, __shfl_xor(dp, 2));        // max over 4 factors (in-slot)
    m = fmaxf(m, __shfl_xor(m, 4));
    float ex = __expf(dp - m);                     // ONE exp per lane
    float es = ex + __shfl_xor(ex, 2);
    es += __shfl_xor(es, 4);
    float p = valid ? (ex / es) : 0.f;             // own factor's softmax weight
#pragma unroll
    for (int j = 0; j < 16; ++j) a[j] = fmaf(p, t[j], a[j]);
  }
#pragma unroll
  for (int j = 0; j < 16; ++j) {                   // merge the 8 edge-slots
    a[j] += __shfl_xor(a[j], 8);
    a[j] += __shfl_xor(a[j], 16);
    a[j] += __shfl_xor(a[j], 32);
  }
  const u32* fp = fac + (size_t)n * ROW_DW + 8 * k;
  uint4 f0 = *(const uint4*)fp, f1 = *(const uint4*)(fp + 4);
  a[0]+=bf_lo(f0.x); a[1]+=bf_hi(f0.x); a[2]+=bf_lo(f0.y); a[3]+=bf_hi(f0.y);
  a[4]+=bf_lo(f0.z); a[5]+=bf_hi(f0.z); a[6]+=bf_lo(f0.w); a[7]+=bf_hi(f0.w);
  a[8]+=bf_lo(f1.x); a[9]+=bf_hi(f1.x); a[10]+=bf_lo(f1.y); a[11]+=bf_hi(f1.y);
  a[12]+=bf_lo(f1.z); a[13]+=bf_hi(f1.z); a[14]+=bf_lo(f1.w); a[15]+=bf_hi(f1.w);
  float ss = 0.f;
#pragma unroll
  for (int j = 0; j < 16; ++j) ss = fmaf(a[j], a[j], ss);
  ss += __shfl_xor(ss, 1);                         // factor sumsq (2-lane group)
  float inv = 1.0f / fmaxf(sqrtf(ss), 1e-12f);
  if (s == 0) {
    float* op = outp + (size_t)n * DIM + 16 * k;
    *(float4*)op        = make_float4(a[0]*inv, a[1]*inv, a[2]*inv, a[3]*inv);
    *(float4*)(op + 4)  = make_float4(a[4]*inv, a[5]*inv, a[6]*inv, a[7]*inv);
    *(float4*)(op + 8)  = make_float4(a[8]*inv, a[9]*inv, a[10]*inv, a[11]*inv);
    *(float4*)(op + 12) = make_float4(a[12]*inv, a[13]*inv, a[14]*inv, a[15]*inv);
  }
}

extern "C" void kernel_launch(void* const* d_in, const int* in_sizes, int n_in,
                              void* d_out, int out_size, void* d_ws, size_t ws_size,
                              hipStream_t stream) {
  int ie = 0, iw = 1, ib = 2, ir = 3, ic = 4;
  if (n_in == 5) {
    int best = -1, besti = 0;
    for (int i = 0; i < 5; ++i) if (in_sizes[i] > best) { best = in_sizes[i]; besti = i; }
    ie = besti; iw = -1; ib = -1; ir = -1; ic = -1;
    for (int i = 0; i < 5; ++i) {
      if (i == ie) continue;
      if (in_sizes[i] == 16384 && iw < 0) iw = i;
      else if (in_sizes[i] == 128 && ib < 0) ib = i;
      else if (ir < 0) ir = i;
      else ic = i;
    }
    if (iw < 0 || ib < 0 || ir < 0 || ic < 0) { ie = 0; iw = 1; ib = 2; ir = 3; ic = 4; }
  }
  const float* emb = (const float*)d_in[ie];   // (N,128) fp32
  const float* W   = (const float*)d_in[iw];   // (4,128,32) fp32
  const float* B   = (const float*)d_in[ib];   // (4,1,32) fp32
  const int* row   = (const int*)d_in[ir];     // (E,)
  const int* col   = (const int*)d_in[ic];     // (E,)
  int N = in_sizes[ie] / DIM;
  int E = in_sizes[ir];
  float* out = (float*)d_out;                  // (N,128) fp32
  float pscale = 8.0f / (float)N;              // row -> XCD partition

  // workspace (~33.3 MB): fac | bfrag | cnt | offs | cur | bsum | ccol
  char* ws = (char*)d_ws;
  u16* fac   = (u16*)ws;                       // N*128 u16 (16B aligned)
  u16* bfrag = fac + (size_t)N * DIM;          // 16384 u16 (32 KB)
  int* cnt   = (int*)(bfrag + 16384);          // N
  int* offs  = cnt + N;                        // N+1
  int* cur   = offs + N + 1;                   // N
  int nb_scan = (N + 1023) / 1024;
  int* bsum  = cur + N;                        // nb_scan+1
  int* ccol  = bsum + nb_scan + 1;             // E

  prep_bfrag_kernel<<<64, 256, 0, stream>>>(W, B, bfrag);
  fac_mfma_kernel<<<(N + 63) / 64, 256, 0, stream>>>(emb, (const short8*)bfrag, fac, N);
  zero_int_kernel<<<(N + 255) / 256, 256, 0, stream>>>(cnt, N);
  hist_kernel<<<2048, 256, 0, stream>>>(row, cnt, E, N, pscale);
  scan1_kernel<<<nb_scan, 256, 0, stream>>>(cnt, offs, bsum, N);
  scan2_kernel<<<1, 1024, 0, stream>>>(bsum, nb_scan);
  scan3_kernel<<<(N + 255) / 256, 256, 0, stream>>>(offs, bsum, cur, N, nb_scan);
  scatter_kernel<<<2048, 256, 0, stream>>>(row, col, cur, ccol, E, N, pscale);
  // iter 1: head = fac (bf16) -> d_out (fp32); iter 2: head = d_out -> d_out in-place
  edge_kernel<<<(N + 3) / 4, 256, 0, stream>>>(fac, 1, (const u32*)fac, offs, ccol, out, N, E);
  edge_kernel<<<(N + 3) / 4, 256, 0, stream>>>(out, 0, (const u32*)fac, offs, ccol, out, N, E);
}

// Round 11
// 411.931 us; speedup vs baseline: 1.1126x; 1.1126x over previous
//
#include <hip/hip_runtime.h>

typedef unsigned int u32;
typedef unsigned short u16;
typedef __attribute__((ext_vector_type(8))) short short8;   // 8 bf16 (4 VGPRs)
typedef __attribute__((ext_vector_type(4))) float f32x4;    // MFMA acc

#define DIM 128      // 4 factors * 32 cols
#define ROW_DW 64    // fac row = 64 dwords (bf16 pairs)

__device__ __forceinline__ float bf_lo(u32 u){ return __uint_as_float(u << 16); }
__device__ __forceinline__ float bf_hi(u32 u){ return __uint_as_float(u & 0xffff0000u); }
__device__ __forceinline__ u16 f2bf(float x){
  u32 u = __float_as_uint(x);
  return (u16)((u + 0x7fffu + ((u >> 16) & 1u)) >> 16);  // RNE
}

// merged: B-fragment prep (16384 elems) + cnt zeroing (N elems)
__global__ void setup_kernel(const float* __restrict__ W, const float* __restrict__ B,
                             u16* __restrict__ frag, int* __restrict__ cnt, int N){
  int i = blockIdx.x * 256 + threadIdx.x;
  if (i < 16384) {
    int j = i & 7, lane = (i >> 3) & 63, ct = (i >> 9) & 7, kt = i >> 12;
    int d = kt * 32 + (lane >> 4) * 8 + j;
    int c = ct * 16 + (lane & 15);
    int f = c >> 5, k = c & 31;
    frag[i] = f2bf(W[f * 4096 + d * 32 + k] + B[f * 32 + k]);  // W:(4,128,32) b:(4,1,32)
  }
  if (i < N) cnt[i] = 0;
}

// fac = l2norm_f(leaky(emb @ wb)) via MFMA. Wave handles 16 nodes x 128 cols.
__global__ __launch_bounds__(256) void fac_mfma_kernel(const float* __restrict__ emb,
                                                       const short8* __restrict__ bfrag,
                                                       u16* __restrict__ fac, int N){
  int lane = threadIdx.x & 63;
  int nb = blockIdx.x * 64 + (threadIdx.x >> 6) * 16;
  if (nb >= N) return;
  int quad = lane >> 4, lo = lane & 15;
  int arow = nb + lo; if (arow >= N) arow = N - 1;
  const float* ap = emb + (size_t)arow * DIM + quad * 8;
  f32x4 acc[8];
#pragma unroll
  for (int ct = 0; ct < 8; ++ct) acc[ct] = (f32x4){0.f, 0.f, 0.f, 0.f};
#pragma unroll
  for (int kt = 0; kt < 4; ++kt) {
    float4 e0 = *(const float4*)(ap + kt * 32);
    float4 e1 = *(const float4*)(ap + kt * 32 + 4);
    short8 afr;
    afr[0] = (short)f2bf(e0.x); afr[1] = (short)f2bf(e0.y);
    afr[2] = (short)f2bf(e0.z); afr[3] = (short)f2bf(e0.w);
    afr[4] = (short)f2bf(e1.x); afr[5] = (short)f2bf(e1.y);
    afr[6] = (short)f2bf(e1.z); afr[7] = (short)f2bf(e1.w);
#pragma unroll
    for (int ct = 0; ct < 8; ++ct) {
      short8 bfr = bfrag[(kt * 8 + ct) * 64 + lane];
      acc[ct] = __builtin_amdgcn_mfma_f32_16x16x32_bf16(afr, bfr, acc[ct], 0, 0, 0);
    }
  }
  float v[8][4];
#pragma unroll
  for (int ct = 0; ct < 8; ++ct)
#pragma unroll
    for (int i = 0; i < 4; ++i) {
      float x = acc[ct][i];
      v[ct][i] = x > 0.f ? x : 0.2f * x;
    }
  float inv[4][4];   // [i][f]
#pragma unroll
  for (int i = 0; i < 4; ++i)
#pragma unroll
    for (int f = 0; f < 4; ++f) {
      float ss = v[2 * f][i] * v[2 * f][i] + v[2 * f + 1][i] * v[2 * f + 1][i];
      ss += __shfl_xor(ss, 1); ss += __shfl_xor(ss, 2);
      ss += __shfl_xor(ss, 4); ss += __shfl_xor(ss, 8);
      inv[i][f] = 1.0f / fmaxf(sqrtf(ss), 1e-12f);
    }
#pragma unroll
  for (int i = 0; i < 4; ++i) {
    int node = nb + quad * 4 + i;
    if (node >= N) continue;
#pragma unroll
    for (int ct = 0; ct < 8; ++ct)
      fac[(size_t)node * DIM + ct * 16 + lo] = f2bf(v[ct][i] * inv[i][ct >> 1]);
  }
}

// XCD-partitioned histogram: block (b&7) handles rows with part(r)==(b&7).
__global__ void hist_kernel(const int* __restrict__ row, int* __restrict__ cnt,
                            int E, int N, float pscale){
  int xcd = blockIdx.x & 7;
  int base = (blockIdx.x >> 3) * blockDim.x + threadIdx.x;
  int stride = (gridDim.x >> 3) * blockDim.x;
  for (int e = base; e < E; e += stride) {
    int r = row[e];
    if ((u32)r >= (u32)N) continue;
    int part = (int)((float)r * pscale);
    part = part > 7 ? 7 : part;
    if (part != xcd) continue;
    atomicAdd(&cnt[r], 1);
  }
}

// ---- 3-phase exclusive scan of cnt[0..N) -> offs[0..N], bsum scratch ----
__global__ __launch_bounds__(256) void scan1_kernel(const int* __restrict__ cnt,
                                                    int* __restrict__ offs,
                                                    int* __restrict__ bsum, int N){
  __shared__ int sh[256];
  int tid = threadIdx.x;
  int idx = blockIdx.x * 1024 + tid * 4;
  int v0 = (idx     < N) ? cnt[idx]     : 0;
  int v1 = (idx + 1 < N) ? cnt[idx + 1] : 0;
  int v2 = (idx + 2 < N) ? cnt[idx + 2] : 0;
  int v3 = (idx + 3 < N) ? cnt[idx + 3] : 0;
  sh[tid] = v0 + v1 + v2 + v3;
  __syncthreads();
  for (int off = 1; off < 256; off <<= 1) {
    int v = (tid >= off) ? sh[tid - off] : 0;
    __syncthreads();
    sh[tid] += v;
    __syncthreads();
  }
  int ex = (tid == 0) ? 0 : sh[tid - 1];
  if (tid == 255) bsum[blockIdx.x] = sh[255];
  if (idx     < N) offs[idx]     = ex;
  if (idx + 1 < N) offs[idx + 1] = ex + v0;
  if (idx + 2 < N) offs[idx + 2] = ex + v0 + v1;
  if (idx + 3 < N) offs[idx + 3] = ex + v0 + v1 + v2;
}

__global__ __launch_bounds__(1024) void scan2_kernel(int* __restrict__ bsum, int B){
  __shared__ int sh[1024];
  int tid = threadIdx.x;
  sh[tid] = (tid < B) ? bsum[tid] : 0;
  __syncthreads();
  for (int off = 1; off < 1024; off <<= 1) {
    int v = (tid >= off) ? sh[tid - off] : 0;
    __syncthreads();
    sh[tid] += v;
    __syncthreads();
  }
  if (tid < B) bsum[tid] = (tid == 0) ? 0 : sh[tid - 1];
  if (tid == B - 1) bsum[B] = sh[tid];
}

__global__ void scan3_kernel(int* __restrict__ offs, const int* __restrict__ bsum,
                             int* __restrict__ cur, int N, int B){
  int i = blockIdx.x * blockDim.x + threadIdx.x;
  if (i < N) {
    int v = offs[i] + bsum[i >> 10];
    offs[i] = v;
    cur[i] = v;
  }
  if (i == 0) offs[N] = bsum[B];
}

// XCD-partitioned scatter: ccol lines for a row-range stay in one XCD's L2.
__global__ void scatter_kernel(const int* __restrict__ row, const int* __restrict__ col,
                               int* __restrict__ cur, int* __restrict__ ccol,
                               int E, int N, float pscale){
  int xcd = blockIdx.x & 7;
  int base = (blockIdx.x >> 3) * blockDim.x + threadIdx.x;
  int stride = (gridDim.x >> 3) * blockDim.x;
  for (int e = base; e < E; e += stride) {
    int r = row[e];
    if ((u32)r >= (u32)N) continue;
    int part = (int)((float)r * pscale);
    part = part > 7 ? 7 : part;
    if (part != xcd) continue;
    int pos = atomicAdd(&cur[r], 1);
    if ((u32)pos < (u32)E) ccol[pos] = col[e];
  }
}

// FUSED both propagation iterations. One wave per node; 16-lane quad per edge
// (4 in flight); lane (q,k) owns comps [8k,8k+8) (factor k>>2).
// Pass 1: head = fac[n]; pass 2: head = out1[n] (registers; tails always fac).
// Pass-2 re-gathers the same ~deg rows -> L1/L2 hot. Softmax: ONE exp/lane.
__global__ __launch_bounds__(256) void edge_fused_kernel(const u32* __restrict__ fac,
                                                         const int* __restrict__ offs,
                                                         const int* __restrict__ ccol,
                                                         float* __restrict__ outp,
                                                         int N, int E){
  int lane = threadIdx.x & 63;
  int n = blockIdx.x * 4 + (threadIdx.x >> 6);
  if (n >= N) return;
  int q = lane >> 4, k = lane & 15;
  uint4 fv = *(const uint4*)(fac + (size_t)n * ROW_DW + 4 * k);
  float f[8];
  f[0]=bf_lo(fv.x); f[1]=bf_hi(fv.x); f[2]=bf_lo(fv.y); f[3]=bf_hi(fv.y);
  f[4]=bf_lo(fv.z); f[5]=bf_hi(fv.z); f[6]=bf_lo(fv.w); f[7]=bf_hi(fv.w);
  int beg = offs[n], end = offs[n + 1];
  if (beg < 0) beg = 0;
  if (end > E) end = E;
  float h[8], o[8];
#pragma unroll
  for (int j = 0; j < 8; ++j) h[j] = f[j];
  for (int pass = 0; pass < 2; ++pass) {
    float a[8];
#pragma unroll
    for (int j = 0; j < 8; ++j) a[j] = 0.f;
    for (int e0 = beg; e0 < end; e0 += 4) {
      int e = e0 + q;
      int valid = (e < end) ? 1 : 0;
      int c = valid ? ccol[e] : 0;
      if ((u32)c >= (u32)N) c = 0;
      uint4 tv = *(const uint4*)(fac + (size_t)c * ROW_DW + 4 * k);
      float t[8];
      t[0]=bf_lo(tv.x); t[1]=bf_hi(tv.x); t[2]=bf_lo(tv.y); t[3]=bf_hi(tv.y);
      t[4]=bf_lo(tv.z); t[5]=bf_hi(tv.z); t[6]=bf_lo(tv.w); t[7]=bf_hi(tv.w);
      float dp = 0.f;
#pragma unroll
      for (int j = 0; j < 8; ++j) dp = fmaf(h[j], t[j], dp);
      dp += __shfl_xor(dp, 1); dp += __shfl_xor(dp, 2);  // own factor's full dot
      float m = fmaxf(dp, __shfl_xor(dp, 4));            // max over 4 factors
      m = fmaxf(m, __shfl_xor(m, 8));
      float ex = __expf(dp - m);                         // ONE exp per lane
      float es = ex + __shfl_xor(ex, 4);
      es += __shfl_xor(es, 8);
      float p = valid ? (ex / es) : 0.f;                 // own factor's weight
#pragma unroll
      for (int j = 0; j < 8; ++j) a[j] = fmaf(p, t[j], a[j]);
    }
#pragma unroll
    for (int j = 0; j < 8; ++j) {                        // merge the 4 edge-slots
      a[j] += __shfl_xor(a[j], 16);
      a[j] += __shfl_xor(a[j], 32);
      a[j] += f[j];                                      // + fac[n]
    }
    float ss = 0.f;
#pragma unroll
    for (int j = 0; j < 8; ++j) ss = fmaf(a[j], a[j], ss);
    ss += __shfl_xor(ss, 1); ss += __shfl_xor(ss, 2);    // per-factor sumsq
    float inv = 1.0f / fmaxf(sqrtf(ss), 1e-12f);
#pragma unroll
    for (int j = 0; j < 8; ++j) { o[j] = a[j] * inv; h[j] = o[j]; }
  }
  if (q == 0) {
    float* op = outp + (size_t)n * DIM + 8 * k;
    *(float4*)op       = make_float4(o[0], o[1], o[2], o[3]);
    *(float4*)(op + 4) = make_float4(o[4], o[5], o[6], o[7]);
  }
}

extern "C" void kernel_launch(void* const* d_in, const int* in_sizes, int n_in,
                              void* d_out, int out_size, void* d_ws, size_t ws_size,
                              hipStream_t stream) {
  int ie = 0, iw = 1, ib = 2, ir = 3, ic = 4;
  if (n_in == 5) {
    int best = -1, besti = 0;
    for (int i = 0; i < 5; ++i) if (in_sizes[i] > best) { best = in_sizes[i]; besti = i; }
    ie = besti; iw = -1; ib = -1; ir = -1; ic = -1;
    for (int i = 0; i < 5; ++i) {
      if (i == ie) continue;
      if (in_sizes[i] == 16384 && iw < 0) iw = i;
      else if (in_sizes[i] == 128 && ib < 0) ib = i;
      else if (ir < 0) ir = i;
      else ic = i;
    }
    if (iw < 0 || ib < 0 || ir < 0 || ic < 0) { ie = 0; iw = 1; ib = 2; ir = 3; ic = 4; }
  }
  const float* emb = (const float*)d_in[ie];   // (N,128) fp32
  const float* W   = (const float*)d_in[iw];   // (4,128,32) fp32
  const float* B   = (const float*)d_in[ib];   // (4,1,32) fp32
  const int* row   = (const int*)d_in[ir];     // (E,)
  const int* col   = (const int*)d_in[ic];     // (E,)
  int N = in_sizes[ie] / DIM;
  int E = in_sizes[ir];
  float* out = (float*)d_out;                  // (N,128) fp32
  float pscale = 8.0f / (float)N;              // row -> XCD partition

  // workspace (~33.3 MB): fac | bfrag | cnt | offs | cur | bsum | ccol
  char* ws = (char*)d_ws;
  u16* fac   = (u16*)ws;                       // N*128 u16 (16B aligned)
  u16* bfrag = fac + (size_t)N * DIM;          // 16384 u16 (32 KB)
  int* cnt   = (int*)(bfrag + 16384);          // N
  int* offs  = cnt + N;                        // N+1
  int* cur   = offs + N + 1;                   // N
  int nb_scan = (N + 1023) / 1024;
  int* bsum  = cur + N;                        // nb_scan+1
  int* ccol  = bsum + nb_scan + 1;             // E

  int nsetup = (N > 16384 ? N : 16384);
  setup_kernel<<<(nsetup + 255) / 256, 256, 0, stream>>>(W, B, bfrag, cnt, N);
  fac_mfma_kernel<<<(N + 63) / 64, 256, 0, stream>>>(emb, (const short8*)bfrag, fac, N);
  hist_kernel<<<2048, 256, 0, stream>>>(row, cnt, E, N, pscale);
  scan1_kernel<<<nb_scan, 256, 0, stream>>>(cnt, offs, bsum, N);
  scan2_kernel<<<1, 1024, 0, stream>>>(bsum, nb_scan);
  scan3_kernel<<<(N + 255) / 256, 256, 0, stream>>>(offs, bsum, cur, N, nb_scan);
  scatter_kernel<<<2048, 256, 0, stream>>>(row, col, cur, ccol, E, N, pscale);
  edge_fused_kernel<<<(N + 3) / 4, 256, 0, stream>>>((const u32*)fac, offs, ccol, out, N, E);
}